// Round 1
// baseline (2605.214 us; speedup 1.0000x reference)
//
#include <hip/hip_runtime.h>
#include <math.h>

#define NB  8
#define SEQ 2048
#define DIM 512

// ---------------------------------------------------------------------------
// Y[m][e] = sum_d X[m][d] * W[e][d] + bias[e]        (X: M x 512, W: 512 x 512)
// block tile 64(m) x 64(e), K-chunk 16, 256 threads, 4x4 microtile
// ---------------------------------------------------------------------------
__global__ __launch_bounds__(256)
void proj_gemm(const float* __restrict__ X, const float* __restrict__ W,
               const float* __restrict__ bias, float* __restrict__ Y)
{
    __shared__ float Xs[16][64];   // [k][m] transposed for b128 compute reads
    __shared__ float Ws[16][64];   // [k][e]

    const int t   = threadIdx.x;
    const int ty  = t >> 4;        // 0..15  (m micro)
    const int tx  = t & 15;        // 0..15  (e micro)
    const int m0  = blockIdx.x * 64;
    const int e0  = blockIdx.y * 64;
    const int lrow = t >> 2;       // 0..63
    const int lq   = t & 3;        // 0..3

    const float* Xp = X + (size_t)(m0 + lrow) * DIM + lq * 4;
    const float* Wp = W + (size_t)(e0 + lrow) * DIM + lq * 4;

    float acc[4][4];
#pragma unroll
    for (int i = 0; i < 4; i++)
#pragma unroll
        for (int j = 0; j < 4; j++) acc[i][j] = 0.f;

    for (int k0 = 0; k0 < DIM; k0 += 16) {
        float4 xv = *(const float4*)(Xp + k0);
        float4 wv = *(const float4*)(Wp + k0);
        __syncthreads();
        Xs[lq*4+0][lrow] = xv.x; Xs[lq*4+1][lrow] = xv.y;
        Xs[lq*4+2][lrow] = xv.z; Xs[lq*4+3][lrow] = xv.w;
        Ws[lq*4+0][lrow] = wv.x; Ws[lq*4+1][lrow] = wv.y;
        Ws[lq*4+2][lrow] = wv.z; Ws[lq*4+3][lrow] = wv.w;
        __syncthreads();
#pragma unroll
        for (int kk = 0; kk < 16; kk++) {
            float xa[4], wb[4];
            *(float4*)xa = *(const float4*)&Xs[kk][ty*4];
            *(float4*)wb = *(const float4*)&Ws[kk][tx*4];
#pragma unroll
            for (int i = 0; i < 4; i++)
#pragma unroll
                for (int j = 0; j < 4; j++)
                    acc[i][j] = fmaf(xa[i], wb[j], acc[i][j]);
        }
    }

    float bv[4];
    *(float4*)bv = *(const float4*)(bias + e0 + tx*4);
#pragma unroll
    for (int i = 0; i < 4; i++) {
        float4 o;
        o.x = acc[i][0] + bv[0];
        o.y = acc[i][1] + bv[1];
        o.z = acc[i][2] + bv[2];
        o.w = acc[i][3] + bv[3];
        *(float4*)(Y + (size_t)(m0 + ty*4 + i) * DIM + e0 + tx*4) = o;
    }
}

// ---------------------------------------------------------------------------
// flash attention: h = softmax(q @ ctx^T * scale) @ v, written IN-PLACE over q
// block: 32 q-rows of one batch; key tiles of 64; online softmax.
// thread (ty,tx): rows {2ty,2ty+1}; S keys {4tx..4tx+3};
//                 h cols {4tx..+3, 4tx+64..+67} per 128-wide d-chunk c=0..3
// ---------------------------------------------------------------------------
__global__ __launch_bounds__(256)
void flash_attn(float* qh, const float* __restrict__ ctx, const float* __restrict__ vp)
{
    __shared__ float Qs[32][34];    // [d][m]  (pad 34: conflict-free + 8B align)
    __shared__ float Ks[32][68];    // [d][k]  (pad 68: 16B align, low conflict)
    __shared__ float Pr[32][68];    // [m][k]
    __shared__ float Vs[64][128];   // [k][d-chunk]

    const int t  = threadIdx.x;
    const int ty = t >> 4;          // 0..15
    const int tx = t & 15;          // 0..15
    const int b  = blockIdx.y;
    const int m0 = blockIdx.x * 32;

    float*       qb = qh + ((size_t)b * SEQ + m0) * DIM;
    const float* kb = ctx + (size_t)b * SEQ * DIM;
    const float* vb = vp  + (size_t)b * SEQ * DIM;

    const float scale = 0.044194173824159216f;  // 1/sqrt(512)

    float hacc[2][4][8];
#pragma unroll
    for (int i = 0; i < 2; i++)
#pragma unroll
        for (int c = 0; c < 4; c++)
#pragma unroll
            for (int x = 0; x < 8; x++) hacc[i][c][x] = 0.f;

    float M[2] = { -INFINITY, -INFINITY };
    float L[2] = { 0.f, 0.f };

    const int qrow = t >> 3;        // 0..31
    const int qq   = t & 7;         // 0..7
    const int vrow = t >> 4;        // 0..15
    const int vcq  = t & 15;        // 0..15

    for (int k0 = 0; k0 < SEQ; k0 += 64) {
        // ---------------- S = q @ K^T  (32 x 64), d-chunks of 32 ----------------
        float s[2][4] = { {0,0,0,0}, {0,0,0,0} };
        for (int dc = 0; dc < DIM; dc += 32) {
            float4 qv  = *(const float4*)(qb + (size_t)qrow * DIM + dc + qq*4);
            float4 k0v = *(const float4*)(kb + (size_t)(k0 + qrow)      * DIM + dc + qq*4);
            float4 k1v = *(const float4*)(kb + (size_t)(k0 + 32 + qrow) * DIM + dc + qq*4);
            __syncthreads();
            Qs[qq*4+0][qrow] = qv.x;  Qs[qq*4+1][qrow] = qv.y;
            Qs[qq*4+2][qrow] = qv.z;  Qs[qq*4+3][qrow] = qv.w;
            Ks[qq*4+0][qrow] = k0v.x; Ks[qq*4+1][qrow] = k0v.y;
            Ks[qq*4+2][qrow] = k0v.z; Ks[qq*4+3][qrow] = k0v.w;
            Ks[qq*4+0][32+qrow] = k1v.x; Ks[qq*4+1][32+qrow] = k1v.y;
            Ks[qq*4+2][32+qrow] = k1v.z; Ks[qq*4+3][32+qrow] = k1v.w;
            __syncthreads();
#pragma unroll
            for (int dd = 0; dd < 32; dd++) {
                float qa[2], ka[4];
                *(float2*)qa = *(const float2*)&Qs[dd][2*ty];
                *(float4*)ka = *(const float4*)&Ks[dd][4*tx];
#pragma unroll
                for (int i = 0; i < 2; i++)
#pragma unroll
                    for (int j = 0; j < 4; j++)
                        s[i][j] = fmaf(qa[i], ka[j], s[i][j]);
            }
        }

        // ---------------- online softmax over this key tile ----------------
        float al[2];
#pragma unroll
        for (int i = 0; i < 2; i++) {
#pragma unroll
            for (int j = 0; j < 4; j++) s[i][j] *= scale;
            float mx = fmaxf(fmaxf(s[i][0], s[i][1]), fmaxf(s[i][2], s[i][3]));
#pragma unroll
            for (int off = 1; off < 16; off <<= 1)
                mx = fmaxf(mx, __shfl_xor(mx, off, 64));
            float Mn = fmaxf(M[i], mx);
            al[i] = __expf(M[i] - Mn);
            float r = 0.f;
#pragma unroll
            for (int j = 0; j < 4; j++) { s[i][j] = __expf(s[i][j] - Mn); r += s[i][j]; }
#pragma unroll
            for (int off = 1; off < 16; off <<= 1)
                r += __shfl_xor(r, off, 64);
            L[i] = L[i] * al[i] + r;
            M[i] = Mn;
        }
#pragma unroll
        for (int i = 0; i < 2; i++)
#pragma unroll
            for (int c = 0; c < 4; c++)
#pragma unroll
                for (int x = 0; x < 8; x++) hacc[i][c][x] *= al[i];

        __syncthreads();   // previous tile's PV reads of Pr are done
        *(float4*)&Pr[2*ty+0][4*tx] = make_float4(s[0][0], s[0][1], s[0][2], s[0][3]);
        *(float4*)&Pr[2*ty+1][4*tx] = make_float4(s[1][0], s[1][1], s[1][2], s[1][3]);

        // ---------------- h += P @ V, d-chunks of 128 ----------------
        for (int c = 0; c < 4; c++) {
            float4 vld[8];
#pragma unroll
            for (int p = 0; p < 4; p++)
#pragma unroll
                for (int q = 0; q < 2; q++)
                    vld[p*2+q] = *(const float4*)(vb + (size_t)(k0 + vrow + 16*p) * DIM
                                                  + c*128 + vcq*4 + 64*q);
            __syncthreads();   // previous chunk's Vs reads done; Pr stores ordered
#pragma unroll
            for (int p = 0; p < 4; p++)
#pragma unroll
                for (int q = 0; q < 2; q++)
                    *(float4*)&Vs[vrow + 16*p][vcq*4 + 64*q] = vld[p*2+q];
            __syncthreads();
#pragma unroll
            for (int ks = 0; ks < 4; ks++) {
                float p0[16], p1[16];
#pragma unroll
                for (int u = 0; u < 4; u++) {
                    *(float4*)&p0[u*4] = *(const float4*)&Pr[2*ty+0][ks*16 + u*4];
                    *(float4*)&p1[u*4] = *(const float4*)&Pr[2*ty+1][ks*16 + u*4];
                }
#pragma unroll
                for (int kkk = 0; kkk < 16; kkk++) {
                    float va[4], vb2[4];
                    *(float4*)va  = *(const float4*)&Vs[ks*16+kkk][4*tx];
                    *(float4*)vb2 = *(const float4*)&Vs[ks*16+kkk][4*tx + 64];
#pragma unroll
                    for (int j = 0; j < 4; j++) {
                        hacc[0][c][j]   = fmaf(p0[kkk], va[j],  hacc[0][c][j]);
                        hacc[0][c][4+j] = fmaf(p0[kkk], vb2[j], hacc[0][c][4+j]);
                        hacc[1][c][j]   = fmaf(p1[kkk], va[j],  hacc[1][c][j]);
                        hacc[1][c][4+j] = fmaf(p1[kkk], vb2[j], hacc[1][c][4+j]);
                    }
                }
            }
        }
    }

    // ---------------- epilogue: h = hacc / L, in-place over q rows ----------------
#pragma unroll
    for (int i = 0; i < 2; i++) {
        float inv = 1.0f / L[i];
#pragma unroll
        for (int c = 0; c < 4; c++) {
            float4 o;
            o.x = hacc[i][c][0]*inv; o.y = hacc[i][c][1]*inv;
            o.z = hacc[i][c][2]*inv; o.w = hacc[i][c][3]*inv;
            *(float4*)(qb + (size_t)(2*ty+i) * DIM + c*128 + 4*tx) = o;
            o.x = hacc[i][c][4]*inv; o.y = hacc[i][c][5]*inv;
            o.z = hacc[i][c][6]*inv; o.w = hacc[i][c][7]*inv;
            *(float4*)(qb + (size_t)(2*ty+i) * DIM + c*128 + 4*tx + 64) = o;
        }
    }
}

// ---------------------------------------------------------------------------
extern "C" void kernel_launch(void* const* d_in, const int* in_sizes, int n_in,
                              void* d_out, int out_size, void* d_ws, size_t ws_size,
                              hipStream_t stream)
{
    const float* query   = (const float*)d_in[0];
    const float* context = (const float*)d_in[1];
    const float* Wq      = (const float*)d_in[2];
    const float* bq      = (const float*)d_in[3];
    const float* Wv      = (const float*)d_in[4];
    const float* bv      = (const float*)d_in[5];
    const float* Wo      = (const float*)d_in[6];
    const float* bo      = (const float*)d_in[7];
    float* out = (float*)d_out;

    float* qh  = (float*)d_ws;                       // q, then h in-place (33.5 MB)
    float* vws = qh + (size_t)NB * SEQ * DIM;        // v projection      (33.5 MB)

    dim3 gridP(NB * SEQ / 64, DIM / 64);             // (256, 8)

    proj_gemm<<<gridP, 256, 0, stream>>>(query,   Wq, bq, qh);
    proj_gemm<<<gridP, 256, 0, stream>>>(context, Wv, bv, vws);
    flash_attn<<<dim3(SEQ/32, NB), 256, 0, stream>>>(qh, context, vws);
    proj_gemm<<<gridP, 256, 0, stream>>>(qh, Wo, bo, out);
}

// Round 2
// 896.328 us; speedup vs baseline: 2.9065x; 2.9065x over previous
//
#include <hip/hip_runtime.h>
#include <math.h>

#define NB  8
#define SEQ 2048
#define DIM 512

typedef short v8s __attribute__((ext_vector_type(8)));
typedef float v4f __attribute__((ext_vector_type(4)));

__device__ __forceinline__ unsigned short f2bf(float f) {
    unsigned int u = __float_as_uint(f);
    u += 0x7fffu + ((u >> 16) & 1u);
    return (unsigned short)(u >> 16);
}

// ---------------------------------------------------------------------------
// fp32 GEMM core: Y[m][e] = sum_d X[m][d] * W[e][d] + bias[e]
// 64x64 tile, 256 threads, 4x4 microtile. Three output-format variants.
// ---------------------------------------------------------------------------
#define PROJ_CORE                                                              \
    __shared__ float Xs[16][64];                                               \
    __shared__ float Ws[16][64];                                               \
    const int t   = threadIdx.x;                                               \
    const int ty  = t >> 4;                                                    \
    const int tx  = t & 15;                                                    \
    const int m0  = blockIdx.x * 64;                                           \
    const int e0  = blockIdx.y * 64;                                           \
    const int lrow = t >> 2;                                                   \
    const int lq   = t & 3;                                                    \
    const float* Xp = X + (size_t)(m0 + lrow) * DIM + lq * 4;                  \
    const float* Wp = W + (size_t)(e0 + lrow) * DIM + lq * 4;                  \
    float acc[4][4];                                                           \
    _Pragma("unroll") for (int i = 0; i < 4; i++)                              \
        _Pragma("unroll") for (int j = 0; j < 4; j++) acc[i][j] = 0.f;         \
    for (int k0 = 0; k0 < DIM; k0 += 16) {                                     \
        float4 xv = *(const float4*)(Xp + k0);                                 \
        float4 wv = *(const float4*)(Wp + k0);                                 \
        __syncthreads();                                                       \
        Xs[lq*4+0][lrow] = xv.x; Xs[lq*4+1][lrow] = xv.y;                      \
        Xs[lq*4+2][lrow] = xv.z; Xs[lq*4+3][lrow] = xv.w;                      \
        Ws[lq*4+0][lrow] = wv.x; Ws[lq*4+1][lrow] = wv.y;                      \
        Ws[lq*4+2][lrow] = wv.z; Ws[lq*4+3][lrow] = wv.w;                      \
        __syncthreads();                                                       \
        _Pragma("unroll") for (int kk = 0; kk < 16; kk++) {                    \
            float xa[4], wb[4];                                                \
            *(float4*)xa = *(const float4*)&Xs[kk][ty*4];                      \
            *(float4*)wb = *(const float4*)&Ws[kk][tx*4];                      \
            _Pragma("unroll") for (int i = 0; i < 4; i++)                      \
                _Pragma("unroll") for (int j = 0; j < 4; j++)                  \
                    acc[i][j] = fmaf(xa[i], wb[j], acc[i][j]);                 \
        }                                                                      \
    }                                                                          \
    float bv[4];                                                               \
    *(float4*)bv = *(const float4*)(bias + e0 + tx*4);

// fp32 output, row-major
__global__ __launch_bounds__(256)
void proj_gemm_f32(const float* __restrict__ X, const float* __restrict__ W,
                   const float* __restrict__ bias, float* __restrict__ Y)
{
    PROJ_CORE
#pragma unroll
    for (int i = 0; i < 4; i++) {
        float4 o;
        o.x = acc[i][0] + bv[0]; o.y = acc[i][1] + bv[1];
        o.z = acc[i][2] + bv[2]; o.w = acc[i][3] + bv[3];
        *(float4*)(Y + (size_t)(m0 + ty*4 + i) * DIM + e0 + tx*4) = o;
    }
}

// bf16 output, row-major  (q path)
__global__ __launch_bounds__(256)
void proj_gemm_bf16(const float* __restrict__ X, const float* __restrict__ W,
                    const float* __restrict__ bias, unsigned short* __restrict__ Y)
{
    PROJ_CORE
#pragma unroll
    for (int i = 0; i < 4; i++) {
        ushort4 o;
        o.x = f2bf(acc[i][0] + bv[0]); o.y = f2bf(acc[i][1] + bv[1]);
        o.z = f2bf(acc[i][2] + bv[2]); o.w = f2bf(acc[i][3] + bv[3]);
        *(ushort4*)(Y + (size_t)(m0 + ty*4 + i) * DIM + e0 + tx*4) = o;
    }
}

// bf16 output, transposed per batch: Y[b][e][n]   (v path)
__global__ __launch_bounds__(256)
void proj_gemm_bf16T(const float* __restrict__ X, const float* __restrict__ W,
                     const float* __restrict__ bias, unsigned short* __restrict__ Y)
{
    PROJ_CORE
    const int mb = m0 + ty*4;
    const int bb = mb / SEQ;
    const int nn = mb % SEQ;
#pragma unroll
    for (int j = 0; j < 4; j++) {
        ushort4 o;
        o.x = f2bf(acc[0][j] + bv[j]); o.y = f2bf(acc[1][j] + bv[j]);
        o.z = f2bf(acc[2][j] + bv[j]); o.w = f2bf(acc[3][j] + bv[j]);
        *(ushort4*)(Y + (size_t)bb * DIM * SEQ + (size_t)(e0 + tx*4 + j) * SEQ + nn) = o;
    }
}

// fp32 -> bf16 elementwise (context)
__global__ __launch_bounds__(256)
void conv_bf16(const float* __restrict__ x, unsigned short* __restrict__ y)
{
    int i = blockIdx.x * 256 + threadIdx.x;
    float4 v = ((const float4*)x)[i];
    ushort4 o; o.x = f2bf(v.x); o.y = f2bf(v.y); o.z = f2bf(v.z); o.w = f2bf(v.w);
    ((ushort4*)y)[i] = o;
}

// ---------------------------------------------------------------------------
// MFMA flash attention.  Block = 512 threads (8 waves), 64 q-rows.
// Waves 0-3: compute (16-row strip each for S/softmax; 128 d-cols each for PV).
// Waves 4-7: producers (stage Vt[t] during S-phase, K[t+1] during PV-phase).
// Q held in registers as A-fragments. h accumulators persistent (128 VGPR).
// ---------------------------------------------------------------------------
__global__ __launch_bounds__(512, 2)
void flash_mfma(const unsigned short* __restrict__ qbf,
                const unsigned short* __restrict__ ctxbf,
                const unsigned short* __restrict__ vT,
                float* __restrict__ hout)
{
    __shared__ unsigned short Ks[64][520];   // [key][d]   stride 260 dw (== 4 mod 32)
    __shared__ unsigned short Vs[512][72];   // [d][key]   stride 36 dw  (== 4 mod 32)
    __shared__ unsigned short Ps[4][16][72]; // [strip][row][key]
    __shared__ float alpha[64];

    const int t    = threadIdx.x;
    const int wave = t >> 6;
    const int lane = t & 63;
    const int l15  = lane & 15;
    const int quad = lane >> 4;
    const int b    = blockIdx.y;
    const int m0   = blockIdx.x * 64;

    const unsigned short* ctxb = ctxbf + (size_t)b * SEQ * DIM;
    const unsigned short* vTb  = vT    + (size_t)b * DIM * SEQ;

    // producers: stage K[0]
    if (wave >= 4) {
        const int tp = t - 256;
#pragma unroll
        for (int i = 0; i < 16; i++) {
            int c = tp + 256 * i;           // 4096 16B-chunks = 64 KB
            int row = c >> 6, cq = c & 63;
            v8s val = *(const v8s*)(ctxb + (size_t)row * DIM + cq * 8);
            *(v8s*)&Ks[row][cq * 8] = val;
        }
    }

    // compute waves: Q fragments + state
    v8s qf[16];
    v4f hacc[4][8];
    float M[4], L[4];
    if (wave < 4) {
        const unsigned short* qrow =
            qbf + ((size_t)b * SEQ + m0 + wave * 16 + l15) * DIM;
#pragma unroll
        for (int kc = 0; kc < 16; kc++)
            qf[kc] = *(const v8s*)(qrow + kc * 32 + quad * 8);
#pragma unroll
        for (int g = 0; g < 4; g++)
#pragma unroll
            for (int dt = 0; dt < 8; dt++)
                hacc[g][dt] = (v4f){0.f, 0.f, 0.f, 0.f};
#pragma unroll
        for (int r = 0; r < 4; r++) { M[r] = -INFINITY; L[r] = 0.f; }
    }

    const float scale = 0.044194173824159216f;  // 1/sqrt(512)

    for (int kt = 0; kt < SEQ / 64; kt++) {
        __syncthreads();   // K[kt] staged; Vs free (PV[kt-1] done)
        if (wave < 4) {
            // ---- S = Q . K^T  (16 x 64 per wave) ----
            v4f acc[4];
#pragma unroll
            for (int ct = 0; ct < 4; ct++) acc[ct] = (v4f){0.f, 0.f, 0.f, 0.f};
#pragma unroll
            for (int kc = 0; kc < 16; kc++) {
#pragma unroll
                for (int ct = 0; ct < 4; ct++) {
                    v8s bf = *(const v8s*)&Ks[ct * 16 + l15][kc * 32 + quad * 8];
                    acc[ct] = __builtin_amdgcn_mfma_f32_16x16x32_bf16(qf[kc], bf, acc[ct], 0, 0, 0);
                }
            }
            // ---- online softmax (rows quad*4+r, reduce over 16 lanes of quad) ----
#pragma unroll
            for (int r = 0; r < 4; r++) {
                float s0 = acc[0][r] * scale, s1 = acc[1][r] * scale;
                float s2 = acc[2][r] * scale, s3 = acc[3][r] * scale;
                float mx = fmaxf(fmaxf(s0, s1), fmaxf(s2, s3));
#pragma unroll
                for (int off = 1; off < 16; off <<= 1)
                    mx = fmaxf(mx, __shfl_xor(mx, off, 64));
                float Mn = fmaxf(M[r], mx);
                float al = __expf(M[r] - Mn);
                float p0 = __expf(s0 - Mn), p1 = __expf(s1 - Mn);
                float p2 = __expf(s2 - Mn), p3 = __expf(s3 - Mn);
                float sm = p0 + p1 + p2 + p3;
#pragma unroll
                for (int off = 1; off < 16; off <<= 1)
                    sm += __shfl_xor(sm, off, 64);
                L[r] = L[r] * al + sm;
                M[r] = Mn;
                int row = quad * 4 + r;
                Ps[wave][row][0  + l15] = f2bf(p0);
                Ps[wave][row][16 + l15] = f2bf(p1);
                Ps[wave][row][32 + l15] = f2bf(p2);
                Ps[wave][row][48 + l15] = f2bf(p3);
                alpha[wave * 16 + row] = al;
            }
        } else {
            // ---- stage Vt[kt]: Vs[d][key] from vT[b][d][n] ----
            const int tp = t - 256;
#pragma unroll
            for (int i = 0; i < 16; i++) {
                int c = tp + 256 * i;       // 4096 chunks of 8 keys
                int d = c >> 3, kq = c & 7;
                v8s val = *(const v8s*)(vTb + (size_t)d * SEQ + kt * 64 + kq * 8);
                *(v8s*)&Vs[d][kq * 8] = val;
            }
        }
        __syncthreads();   // P/alpha/Vs ready; K free for restage
        if (wave < 4) {
            // ---- rescale h by alpha, then h += P . V  (64 rows x 128 cols) ----
#pragma unroll
            for (int g = 0; g < 4; g++) {
                v4f al4;
#pragma unroll
                for (int r = 0; r < 4; r++) al4[r] = alpha[g * 16 + quad * 4 + r];
#pragma unroll
                for (int dt = 0; dt < 8; dt++) hacc[g][dt] *= al4;
            }
#pragma unroll
            for (int kc = 0; kc < 2; kc++) {
                v8s pa[4];
#pragma unroll
                for (int g = 0; g < 4; g++)
                    pa[g] = *(const v8s*)&Ps[g][l15][kc * 32 + quad * 8];
#pragma unroll
                for (int dt = 0; dt < 8; dt++) {
                    v8s vb = *(const v8s*)&Vs[wave * 128 + dt * 16 + l15][kc * 32 + quad * 8];
#pragma unroll
                    for (int g = 0; g < 4; g++)
                        hacc[g][dt] = __builtin_amdgcn_mfma_f32_16x16x32_bf16(pa[g], vb, hacc[g][dt], 0, 0, 0);
                }
            }
        } else if (kt + 1 < SEQ / 64) {
            // ---- stage K[kt+1] ----
            const int tp = t - 256;
#pragma unroll
            for (int i = 0; i < 16; i++) {
                int c = tp + 256 * i;
                int row = c >> 6, cq = c & 63;
                v8s val = *(const v8s*)(ctxb + (size_t)((kt + 1) * 64 + row) * DIM + cq * 8);
                *(v8s*)&Ks[row][cq * 8] = val;
            }
        }
    }

    // ---- epilogue: h / L ----
    __syncthreads();
    if (wave < 4) {
#pragma unroll
        for (int r = 0; r < 4; r++)
            alpha[wave * 16 + quad * 4 + r] = 1.0f / L[r];
    }
    __syncthreads();
    if (wave < 4) {
#pragma unroll
        for (int g = 0; g < 4; g++) {
            v4f il4;
#pragma unroll
            for (int r = 0; r < 4; r++) il4[r] = alpha[g * 16 + quad * 4 + r];
#pragma unroll
            for (int dt = 0; dt < 8; dt++) {
                v4f o = hacc[g][dt] * il4;
#pragma unroll
                for (int r = 0; r < 4; r++) {
                    hout[((size_t)b * SEQ + m0 + g * 16 + quad * 4 + r) * DIM
                         + wave * 128 + dt * 16 + l15] = o[r];
                }
            }
        }
    }
}

// ---------------------------------------------------------------------------
extern "C" void kernel_launch(void* const* d_in, const int* in_sizes, int n_in,
                              void* d_out, int out_size, void* d_ws, size_t ws_size,
                              hipStream_t stream)
{
    const float* query   = (const float*)d_in[0];
    const float* context = (const float*)d_in[1];
    const float* Wq      = (const float*)d_in[2];
    const float* bq      = (const float*)d_in[3];
    const float* Wv      = (const float*)d_in[4];
    const float* bv      = (const float*)d_in[5];
    const float* Wo      = (const float*)d_in[6];
    const float* bo      = (const float*)d_in[7];
    float* out = (float*)d_out;

    const size_t NE = (size_t)NB * SEQ * DIM;     // 8.39M elements
    unsigned short* qbf = (unsigned short*)d_ws;  // 16.78 MB
    unsigned short* cbf = qbf + NE;               // 16.78 MB
    float*          hbf = (float*)(cbf + NE);     // 33.55 MB
    unsigned short* vTb = (unsigned short*)d_out; // v^T bf16 staged in d_out (16.78 MB)

    dim3 gridP(NB * SEQ / 64, DIM / 64);          // (256, 8)

    conv_bf16      <<<NE / (4 * 256), 256, 0, stream>>>(context, cbf);
    proj_gemm_bf16 <<<gridP, 256, 0, stream>>>(query,   Wq, bq, qbf);
    proj_gemm_bf16T<<<gridP, 256, 0, stream>>>(context, Wv, bv, vTb);
    flash_mfma     <<<dim3(SEQ / 64, NB), 512, 0, stream>>>(qbf, cbf, vTb, hbf);
    proj_gemm_f32  <<<gridP, 256, 0, stream>>>(hbf, Wo, bo, out);
}

// Round 3
// 345.982 us; speedup vs baseline: 7.5299x; 2.5907x over previous
//
#include <hip/hip_runtime.h>
#include <math.h>

#define NB  8
#define SEQ 2048
#define DIM 512

typedef short v8s __attribute__((ext_vector_type(8)));
typedef float v4f __attribute__((ext_vector_type(4)));

__device__ __forceinline__ unsigned short f2bf(float f) {
    unsigned int u = __float_as_uint(f);
    u += 0x7fffu + ((u >> 16) & 1u);
    return (unsigned short)(u >> 16);
}
__device__ __forceinline__ float bf2f(unsigned short h) {
    return __uint_as_float((unsigned int)h << 16);
}
// async 16B global->LDS. LDS dest = lptr(wave-uniform) + lane*16.
__device__ __forceinline__ void async16(const unsigned short* g, unsigned short* l) {
    __builtin_amdgcn_global_load_lds(
        (const __attribute__((address_space(1))) unsigned int*)g,
        (__attribute__((address_space(3))) unsigned int*)l, 16, 0, 0);
}

// fp32 -> bf16 elementwise
__global__ __launch_bounds__(256)
void conv_bf16(const float* __restrict__ x, unsigned short* __restrict__ y)
{
    int i = blockIdx.x * 256 + threadIdx.x;
    float4 v = ((const float4*)x)[i];
    ushort4 o; o.x = f2bf(v.x); o.y = f2bf(v.y); o.z = f2bf(v.z); o.w = f2bf(v.w);
    ((ushort4*)y)[i] = o;
}

// ---------------------------------------------------------------------------
// Single-bf16 MFMA projection: Y[m][e] = sum_d X[m][d]*W[e][d] + bias[e]
// A = Xbf (bf16, global_load_lds), B = W fp32 converted in-kernel.
// 128x128 tile, BK=64, 256 threads (4 waves), wave owns 32 rows x 128 cols.
// MODE 0: bf16 row-major out.  MODE 1: bf16 transposed out Y[b][e][n].
// ---------------------------------------------------------------------------
template<int MODE>
__global__ __launch_bounds__(256, 2)
void proj_sgl(const unsigned short* __restrict__ Xbf, const float* __restrict__ W,
              const float* __restrict__ bias, unsigned short* __restrict__ Y)
{
    __shared__ __align__(16) unsigned short As[128 * 64];
    __shared__ __align__(16) unsigned short Bs[128 * 64];

    const int t = threadIdx.x, wave = t >> 6, lane = t & 63;
    const int l15 = lane & 15, quad = lane >> 4;
    const int m0 = blockIdx.x * 128, e0 = blockIdx.y * 128;

    v4f hacc[2][8];
#pragma unroll
    for (int mt = 0; mt < 2; mt++)
#pragma unroll
        for (int nt = 0; nt < 8; nt++) hacc[mt][nt] = (v4f){0.f, 0.f, 0.f, 0.f};

    const int lr8 = lane >> 3, lc8 = lane & 7;

#define STAGE_A(bk)                                                            \
    _Pragma("unroll") for (int i = 0; i < 4; i++) {                            \
        int row = wave * 32 + i * 8 + lr8;                                     \
        int lc = lc8 ^ (row & 7);                                              \
        async16(Xbf + (size_t)(m0 + row) * DIM + (bk) * 64 + lc * 8,           \
                &As[(wave * 32 + i * 8) * 64]);                                \
    }
#define STAGE_B(bk)                                                            \
    _Pragma("unroll") for (int j = 0; j < 8; j++) {                            \
        int u = t * 8 + j;                                                     \
        int row = u >> 4, c4 = u & 15;                                         \
        float4 wv = *(const float4*)(W + (size_t)(e0 + row) * DIM + (bk) * 64 + c4 * 4); \
        ushort4 o = make_ushort4(f2bf(wv.x), f2bf(wv.y), f2bf(wv.z), f2bf(wv.w)); \
        int sc = (c4 >> 1) ^ (row & 7);                                        \
        *(ushort4*)&Bs[row * 64 + sc * 8 + (c4 & 1) * 4] = o;                  \
    }

    STAGE_A(0) STAGE_B(0)
    for (int bk = 0; bk < 8; bk++) {
        __syncthreads();
#pragma unroll
        for (int kc = 0; kc < 2; kc++) {
            v8s a[2];
#pragma unroll
            for (int mt = 0; mt < 2; mt++) {
                int row = wave * 32 + mt * 16 + l15;
                a[mt] = *(const v8s*)&As[row * 64 + (((kc * 4 + quad) ^ (row & 7)) * 8)];
            }
#pragma unroll
            for (int nt = 0; nt < 8; nt++) {
                int er = nt * 16 + l15;
                v8s bfr = *(const v8s*)&Bs[er * 64 + (((kc * 4 + quad) ^ (er & 7)) * 8)];
#pragma unroll
                for (int mt = 0; mt < 2; mt++)
                    hacc[mt][nt] = __builtin_amdgcn_mfma_f32_16x16x32_bf16(a[mt], bfr, hacc[mt][nt], 0, 0, 0);
            }
        }
        __syncthreads();
        if (bk + 1 < 8) { STAGE_A(bk + 1) STAGE_B(bk + 1) }
    }
#undef STAGE_A
#undef STAGE_B

#pragma unroll
    for (int mt = 0; mt < 2; mt++)
#pragma unroll
        for (int nt = 0; nt < 8; nt++) {
            int col = e0 + nt * 16 + l15;
            float bb = bias[col];
            if (MODE == 0) {
#pragma unroll
                for (int r = 0; r < 4; r++) {
                    int row = m0 + wave * 32 + mt * 16 + quad * 4 + r;
                    Y[(size_t)row * DIM + col] = f2bf(hacc[mt][nt][r] + bb);
                }
            } else {
                int rowb = m0 + wave * 32 + mt * 16 + quad * 4;
                int bidx = rowb >> 11, n = rowb & 2047;
                ushort4 o = make_ushort4(f2bf(hacc[mt][nt][0] + bb), f2bf(hacc[mt][nt][1] + bb),
                                         f2bf(hacc[mt][nt][2] + bb), f2bf(hacc[mt][nt][3] + bb));
                *(ushort4*)&Y[(size_t)bidx * DIM * SEQ + (size_t)col * SEQ + n] = o;
            }
        }
}

// ---------------------------------------------------------------------------
// Split (hi/lo) MFMA projection for the output layer: fp32-accurate.
// A = h (pre-split hhi/hlo bf16), B = Wo fp32 split in-kernel.
// D ~= Ah*Bh + Al*Bh + Ah*Bl   (error ~2^-18)
// ---------------------------------------------------------------------------
__global__ __launch_bounds__(256, 2)
void proj_split(const unsigned short* __restrict__ Ahi, const unsigned short* __restrict__ Alo,
                const float* __restrict__ W, const float* __restrict__ bias,
                float* __restrict__ Y)
{
    __shared__ __align__(16) unsigned short Ah[128 * 64];
    __shared__ __align__(16) unsigned short Al[128 * 64];
    __shared__ __align__(16) unsigned short Bh[128 * 64];
    __shared__ __align__(16) unsigned short Bl[128 * 64];

    const int t = threadIdx.x, wave = t >> 6, lane = t & 63;
    const int l15 = lane & 15, quad = lane >> 4;
    const int m0 = blockIdx.x * 128, e0 = blockIdx.y * 128;

    v4f hacc[2][8];
#pragma unroll
    for (int mt = 0; mt < 2; mt++)
#pragma unroll
        for (int nt = 0; nt < 8; nt++) hacc[mt][nt] = (v4f){0.f, 0.f, 0.f, 0.f};

    const int lr8 = lane >> 3, lc8 = lane & 7;

#define STAGE_A2(bk)                                                           \
    _Pragma("unroll") for (int i = 0; i < 4; i++) {                            \
        int row = wave * 32 + i * 8 + lr8;                                     \
        int lc = lc8 ^ (row & 7);                                              \
        size_t ga = (size_t)(m0 + row) * DIM + (bk) * 64 + lc * 8;             \
        async16(Ahi + ga, &Ah[(wave * 32 + i * 8) * 64]);                      \
        async16(Alo + ga, &Al[(wave * 32 + i * 8) * 64]);                      \
    }
#define STAGE_B2(bk)                                                           \
    _Pragma("unroll") for (int j = 0; j < 8; j++) {                            \
        int u = t * 8 + j;                                                     \
        int row = u >> 4, c4 = u & 15;                                         \
        float4 wv = *(const float4*)(W + (size_t)(e0 + row) * DIM + (bk) * 64 + c4 * 4); \
        ushort4 oh = make_ushort4(f2bf(wv.x), f2bf(wv.y), f2bf(wv.z), f2bf(wv.w)); \
        ushort4 ol = make_ushort4(f2bf(wv.x - bf2f(oh.x)), f2bf(wv.y - bf2f(oh.y)), \
                                  f2bf(wv.z - bf2f(oh.z)), f2bf(wv.w - bf2f(oh.w))); \
        int sc = (c4 >> 1) ^ (row & 7);                                        \
        int sa = row * 64 + sc * 8 + (c4 & 1) * 4;                             \
        *(ushort4*)&Bh[sa] = oh;                                               \
        *(ushort4*)&Bl[sa] = ol;                                               \
    }

    STAGE_A2(0) STAGE_B2(0)
    for (int bk = 0; bk < 8; bk++) {
        __syncthreads();
#pragma unroll
        for (int kc = 0; kc < 2; kc++) {
            v8s ah[2], al[2];
#pragma unroll
            for (int mt = 0; mt < 2; mt++) {
                int row = wave * 32 + mt * 16 + l15;
                int sa = row * 64 + (((kc * 4 + quad) ^ (row & 7)) * 8);
                ah[mt] = *(const v8s*)&Ah[sa];
                al[mt] = *(const v8s*)&Al[sa];
            }
#pragma unroll
            for (int nt = 0; nt < 8; nt++) {
                int er = nt * 16 + l15;
                int sb = er * 64 + (((kc * 4 + quad) ^ (er & 7)) * 8);
                v8s bh = *(const v8s*)&Bh[sb];
                v8s bl = *(const v8s*)&Bl[sb];
#pragma unroll
                for (int mt = 0; mt < 2; mt++) {
                    hacc[mt][nt] = __builtin_amdgcn_mfma_f32_16x16x32_bf16(ah[mt], bh, hacc[mt][nt], 0, 0, 0);
                    hacc[mt][nt] = __builtin_amdgcn_mfma_f32_16x16x32_bf16(al[mt], bh, hacc[mt][nt], 0, 0, 0);
                    hacc[mt][nt] = __builtin_amdgcn_mfma_f32_16x16x32_bf16(ah[mt], bl, hacc[mt][nt], 0, 0, 0);
                }
            }
        }
        __syncthreads();
        if (bk + 1 < 8) { STAGE_A2(bk + 1) STAGE_B2(bk + 1) }
    }
#undef STAGE_A2
#undef STAGE_B2

#pragma unroll
    for (int mt = 0; mt < 2; mt++)
#pragma unroll
        for (int nt = 0; nt < 8; nt++) {
            int col = e0 + nt * 16 + l15;
            float bb = bias[col];
#pragma unroll
            for (int r = 0; r < 4; r++) {
                int row = m0 + wave * 32 + mt * 16 + quad * 4 + r;
                Y[(size_t)row * DIM + col] = hacc[mt][nt][r] + bb;
            }
        }
}

// ---------------------------------------------------------------------------
// Flash attention v3: 512 threads (8 waves), all compute. 64 q-rows/block.
// S: wave (strip=w&3, half=w>>2) -> 16 rows x 32 keys.  Softmax: fp32 S via
// LDS, 1 row/lane-octet.  PV: wave owns 64 d-cols, V B-frags direct from
// global vT (prefetched).  K staged via swizzled global_load_lds during PV.
// Output: h pre-split into hhi/hlo bf16.
// ---------------------------------------------------------------------------
__global__ __launch_bounds__(512, 2)
void flash_mfma2(const unsigned short* __restrict__ qbf,
                 const unsigned short* __restrict__ ctxbf,
                 const unsigned short* __restrict__ vT,
                 unsigned short* __restrict__ hhi,
                 unsigned short* __restrict__ hlo)
{
    __shared__ __align__(16) unsigned short Ks[64 * 512];  // swizzled [key][d]
    __shared__ __align__(16) unsigned short Ps[64 * 72];   // [row][key] bf16
    __shared__ __align__(16) float Sf[64 * 68];            // [row][key] fp32
    __shared__ float alphaS[64];

    const int t = threadIdx.x;
    const int wave = t >> 6, lane = t & 63;
    const int l15 = lane & 15, quad = lane >> 4;
    const int strip = wave & 3, half = wave >> 2;
    const int lr = lane >> 3, l8 = lane & 7;     // softmax: row wave*8+lr
    const int b = blockIdx.y, m0 = blockIdx.x * 64;

    const unsigned short* ctxb = ctxbf + (size_t)b * SEQ * DIM;
    const unsigned short* vTb  = vT    + (size_t)b * DIM * SEQ;
    const float scale = 0.044194173824159216f;   // 1/sqrt(512)

    // Q fragments: rows m0 + strip*16 + l15 (redundant across key-halves)
    v8s qf[16];
    {
        const unsigned short* qrow = qbf + ((size_t)b * SEQ + m0 + strip * 16 + l15) * DIM;
#pragma unroll
        for (int kc = 0; kc < 16; kc++)
            qf[kc] = *(const v8s*)(qrow + kc * 32 + quad * 8);
    }
    v4f hacc[4][4];   // [Mtile][dt], cols wave*64 + dt*16
#pragma unroll
    for (int m = 0; m < 4; m++)
#pragma unroll
        for (int dt = 0; dt < 4; dt++) hacc[m][dt] = (v4f){0.f, 0.f, 0.f, 0.f};

    float M = -INFINITY, L = 0.f;   // softmax state for row wave*8+lr

    // stage K[0]
#pragma unroll
    for (int i = 0; i < 8; i++) {
        int row = wave * 8 + i;
        async16(ctxb + (size_t)row * DIM + (size_t)(lane ^ (row & 7)) * 8, &Ks[row * 512]);
    }

    for (int kt = 0; kt < SEQ / 64; kt++) {
        __syncthreads();   // B0: K[kt] staged & visible
        // prefetch V fragments for this tile (consumed in PV)
        v8s vf[4][2];
#pragma unroll
        for (int dt = 0; dt < 4; dt++)
#pragma unroll
            for (int kc = 0; kc < 2; kc++)
                vf[dt][kc] = *(const v8s*)(vTb + (size_t)(wave * 64 + dt * 16 + l15) * SEQ
                                           + kt * 64 + kc * 32 + quad * 8);
        // ---- S = Q.K^T: 16 rows x 32 keys per wave ----
        v4f sacc[2];
        sacc[0] = (v4f){0.f, 0.f, 0.f, 0.f};
        sacc[1] = (v4f){0.f, 0.f, 0.f, 0.f};
#pragma unroll
        for (int kc = 0; kc < 16; kc++) {
#pragma unroll
            for (int ct = 0; ct < 2; ct++) {
                int key = half * 32 + ct * 16 + l15;
                v8s kf = *(const v8s*)&Ks[key * 512 + (((kc * 4 + quad) ^ (key & 7)) * 8)];
                sacc[ct] = __builtin_amdgcn_mfma_f32_16x16x32_bf16(qf[kc], kf, sacc[ct], 0, 0, 0);
            }
        }
#pragma unroll
        for (int ct = 0; ct < 2; ct++)
#pragma unroll
            for (int r = 0; r < 4; r++)
                Sf[(strip * 16 + quad * 4 + r) * 68 + half * 32 + ct * 16 + l15] = sacc[ct][r] * scale;
        __syncthreads();   // B1: Sf complete, Ks reads done
        // ---- softmax: row = wave*8+lr, cols l8*8.. ----
        {
            int row = wave * 8 + lr;
            float sv[8];
            *(float4*)&sv[0] = *(const float4*)&Sf[row * 68 + l8 * 8];
            *(float4*)&sv[4] = *(const float4*)&Sf[row * 68 + l8 * 8 + 4];
            float mx = sv[0];
#pragma unroll
            for (int j = 1; j < 8; j++) mx = fmaxf(mx, sv[j]);
#pragma unroll
            for (int off = 1; off < 8; off <<= 1) mx = fmaxf(mx, __shfl_xor(mx, off, 64));
            float Mn = fmaxf(M, mx);
            float al = __expf(M - Mn);
            float sm = 0.f;
            v8s pv;
#pragma unroll
            for (int j = 0; j < 8; j++) {
                float p = __expf(sv[j] - Mn);
                sm += p;
                pv[j] = (short)f2bf(p);
            }
#pragma unroll
            for (int off = 1; off < 8; off <<= 1) sm += __shfl_xor(sm, off, 64);
            L = L * al + sm;
            M = Mn;
            *(v8s*)&Ps[row * 72 + l8 * 8] = pv;
            if (l8 == 0) alphaS[row] = al;
        }
        __syncthreads();   // B2: Ps/alpha ready
        // ---- issue K[kt+1] (in flight across PV; drained at next B0) ----
        if (kt + 1 < SEQ / 64) {
#pragma unroll
            for (int i = 0; i < 8; i++) {
                int row = wave * 8 + i;
                async16(ctxb + (size_t)((kt + 1) * 64 + row) * DIM + (size_t)(lane ^ (row & 7)) * 8,
                        &Ks[row * 512]);
            }
        }
        // ---- PV: rescale + h += P.V ----
#pragma unroll
        for (int m = 0; m < 4; m++) {
            v4f a4;
#pragma unroll
            for (int r = 0; r < 4; r++) a4[r] = alphaS[m * 16 + quad * 4 + r];
#pragma unroll
            for (int dt = 0; dt < 4; dt++) hacc[m][dt] *= a4;
        }
#pragma unroll
        for (int kc = 0; kc < 2; kc++) {
            v8s pa[4];
#pragma unroll
            for (int m = 0; m < 4; m++)
                pa[m] = *(const v8s*)&Ps[(m * 16 + l15) * 72 + kc * 32 + quad * 8];
#pragma unroll
            for (int dt = 0; dt < 4; dt++)
#pragma unroll
                for (int m = 0; m < 4; m++)
                    hacc[m][dt] = __builtin_amdgcn_mfma_f32_16x16x32_bf16(pa[m], vf[dt][kc], hacc[m][dt], 0, 0, 0);
        }
    }

    // ---- epilogue: h/L, split hi/lo ----
    __syncthreads();
    if (l8 == 0) alphaS[wave * 8 + lr] = 1.0f / L;
    __syncthreads();
#pragma unroll
    for (int m = 0; m < 4; m++) {
#pragma unroll
        for (int r = 0; r < 4; r++) {
            float invL = alphaS[m * 16 + quad * 4 + r];
            int grow = m0 + m * 16 + quad * 4 + r;
#pragma unroll
            for (int dt = 0; dt < 4; dt++) {
                float o = hacc[m][dt][r] * invL;
                unsigned short hi = f2bf(o);
                float lof = o - bf2f(hi);
                size_t idx = ((size_t)b * SEQ + grow) * DIM + wave * 64 + dt * 16 + l15;
                hhi[idx] = hi;
                hlo[idx] = f2bf(lof);
            }
        }
    }
}

// ---------------------------------------------------------------------------
extern "C" void kernel_launch(void* const* d_in, const int* in_sizes, int n_in,
                              void* d_out, int out_size, void* d_ws, size_t ws_size,
                              hipStream_t stream)
{
    const float* query   = (const float*)d_in[0];
    const float* context = (const float*)d_in[1];
    const float* Wq      = (const float*)d_in[2];
    const float* bq      = (const float*)d_in[3];
    const float* Wv      = (const float*)d_in[4];
    const float* bv      = (const float*)d_in[5];
    const float* Wo      = (const float*)d_in[6];
    const float* bo      = (const float*)d_in[7];

    const size_t NE = (size_t)NB * SEQ * DIM;          // 8,388,608
    unsigned short* qbf = (unsigned short*)d_ws;       // 16.78 MB
    unsigned short* cbf = qbf + NE;                    // 16.78 MB
    unsigned short* hhi = cbf + NE;                    // 16.78 MB
    unsigned short* hlo = hhi + NE;                    // 16.78 MB  (total 67.1 MB)
    unsigned short* vTb = (unsigned short*)d_out;      // v^T bf16 in d_out[0:NE]
    unsigned short* qx  = ((unsigned short*)d_out) + NE; // query bf16 in d_out[NE:2NE]

    dim3 gridP(128, 4);

    conv_bf16   <<<NE / 1024, 256, 0, stream>>>(query, qx);
    conv_bf16   <<<NE / 1024, 256, 0, stream>>>(context, cbf);
    proj_sgl<0> <<<gridP, 256, 0, stream>>>(qx,  Wq, bq, qbf);
    proj_sgl<1> <<<gridP, 256, 0, stream>>>(cbf, Wv, bv, vTb);
    flash_mfma2 <<<dim3(SEQ / 64, NB), 512, 0, stream>>>(qbf, cbf, vTb, hhi, hlo);
    proj_split  <<<gridP, 256, 0, stream>>>(hhi, hlo, Wo, bo, (float*)d_out);
}